// Round 23
// baseline (176.216 us; speedup 1.0000x reference)
//
#include <hip/hip_runtime.h>
#include <hip/hip_bf16.h>

#define IN_FEAT 256
#define HEADS 4
#define OUT_FEAT 64
#define NEG_SLOPE 0.2f
#define SLOT_CAP 64
#define GWAVES 6              // waves per gemm block (192 rows)

typedef __bf16 bf16x8 __attribute__((ext_vector_type(8)));
typedef float f32x4 __attribute__((ext_vector_type(4)));

__device__ inline unsigned short f2bf(float f) {
    union { float f; unsigned u; } v; v.f = f;
    unsigned r = v.u + 0x7FFF + ((v.u >> 16) & 1);   // RNE, finite inputs
    return (unsigned short)(r >> 16);
}
__device__ inline float bf2f(unsigned short u) {
    union { unsigned u; float f; } v; v.u = ((unsigned)u) << 16; return v.f;
}

// ---------------- merged: XCD-partitioned slot scatter + W bf16 convert -----
__global__ __launch_bounds__(256) void cvt_scatter(const int* __restrict__ ei,
                                                   const float* __restrict__ W,
                                                   unsigned short* __restrict__ Wtb,
                                                   int* __restrict__ cursor,
                                                   unsigned short* __restrict__ slots,
                                                   int E, int N, int NS) {
    const int tid = threadIdx.x;
    if ((int)blockIdx.x < NS) {
        // ---- XCD-partitioned scatter (keeps each dst-range in one L2) ----
        const int part = blockIdx.x & 7;
        const int rsize = (N + 7) >> 3;
        const int lo = part * rsize;
        const int hi = min(lo + rsize, N);
        int lid = ((int)blockIdx.x >> 3) * 256 + tid;
        int lstride = (NS >> 3) * 256;
        for (int e = lid; e < E; e += lstride) {
            int d = ei[E + e];
            if (d < lo || d >= hi) continue;
            int s = ei[e];
            if ((unsigned)s >= (unsigned)N) continue;
            int pos = atomicAdd(&cursor[d], 1);
            if (pos < SLOT_CAP) slots[d * SLOT_CAP + pos] = (unsigned short)s;
        }
        return;
    }
    // ---- W -> Wtb (transposed bf16, pre-swizzled): 8192 chunk-pairs ----
    int idx = ((int)blockIdx.x - NS) * 256 + tid;
    if (idx >= 256 * 32) return;
    int n = idx >> 5, j = idx & 31;
    int g = j >> 3, c = j & 7;
    ushort4 p0, p1;
    p0.x = f2bf(W[(size_t)(j * 8 + 0) * 256 + n]);
    p0.y = f2bf(W[(size_t)(j * 8 + 1) * 256 + n]);
    p0.z = f2bf(W[(size_t)(j * 8 + 2) * 256 + n]);
    p0.w = f2bf(W[(size_t)(j * 8 + 3) * 256 + n]);
    p1.x = f2bf(W[(size_t)(j * 8 + 4) * 256 + n]);
    p1.y = f2bf(W[(size_t)(j * 8 + 5) * 256 + n]);
    p1.z = f2bf(W[(size_t)(j * 8 + 6) * 256 + n]);
    p1.w = f2bf(W[(size_t)(j * 8 + 7) * 256 + n]);
    unsigned short* dst = &Wtb[(size_t)n * 256 + (g * 8 + (c ^ (n & 7))) * 8];
    *reinterpret_cast<ushort4*>(dst) = p0;
    *reinterpret_cast<ushort4*>(dst + 4) = p1;
}

// ---------------- weight-stationary GEMM: Hb = bf16(X @ Wtb^T) + logits -----
// Wtb (128 KB, pre-swizzled) stationary in LDS. 6 waves x 32-row tiles,
// A straight from f32 X (global->reg, f2bf), DISTANCE-2 prefetch (3 named
// register sets), no main-loop barriers. 192-row blocks -> 261 blocks ~ one
// full CU round (vs 196 blocks leaving 60 CUs idle).
__global__ __launch_bounds__(GWAVES * 64) void gemm_ws(
        const float* __restrict__ X, const unsigned short* __restrict__ Wtb,
        const float* __restrict__ att_src, const float* __restrict__ att_dst,
        unsigned short* __restrict__ Hb, float* __restrict__ asrc,
        float* __restrict__ adst, int M) {
    __shared__ __align__(16) unsigned short sB[256 * 256];  // 128 KB, stationary
    __shared__ __align__(16) unsigned short sC[32 * 256];   // 16 KB epilogue
    const int tid = threadIdx.x;
    const int lane = tid & 63;
    const int wid = tid >> 6;
    const int q = lane >> 4;          // 0..3: k-subchunk
    const int lr = lane & 15;         // row-in-fragment / col-in-fragment

    // ---- prologue: copy pre-swizzled Wtb into LDS (8192 uint4) ----
    {
        const uint4* W4 = reinterpret_cast<const uint4*>(Wtb);
        uint4* dB = reinterpret_cast<uint4*>(sB);
        for (int t = tid; t < 8192; t += GWAVES * 64) dB[t] = W4[t];
    }
    __syncthreads();

    const int brow = blockIdx.x * (GWAVES * 32);
    const int r0 = brow + wid * 32;   // this wave's 32-row tile

    f32x4 acc[2][16] = {};
    bf16x8 a0[2], a1[2], a2[2];

#define ALOAD(dst, kc)                                                            \
    {                                                                             \
        int ch = (kc) * 4 + q;                                                    \
        _Pragma("unroll")                                                         \
        for (int m = 0; m < 2; ++m) {                                             \
            int r = r0 + m * 16 + lr;                                             \
            if (r >= M) r = M - 1;                                                \
            const float4 x0 = *reinterpret_cast<const float4*>(                   \
                &X[(size_t)r * 256 + ch * 8]);                                    \
            const float4 x1 = *reinterpret_cast<const float4*>(                   \
                &X[(size_t)r * 256 + ch * 8 + 4]);                                \
            union { ushort4 u2[2]; bf16x8 v; } cv;                                \
            cv.u2[0].x = f2bf(x0.x); cv.u2[0].y = f2bf(x0.y);                     \
            cv.u2[0].z = f2bf(x0.z); cv.u2[0].w = f2bf(x0.w);                     \
            cv.u2[1].x = f2bf(x1.x); cv.u2[1].y = f2bf(x1.y);                     \
            cv.u2[1].z = f2bf(x1.z); cv.u2[1].w = f2bf(x1.w);                     \
            dst[m] = cv.v;                                                        \
        }                                                                         \
    }

#define COMPK(areg, kc)                                                           \
    {                                                                             \
        __builtin_amdgcn_s_setprio(1);                                            \
        _Pragma("unroll")                                                         \
        for (int nf = 0; nf < 16; ++nf) {                                         \
            int n = nf * 16 + lr;                                                 \
            int ch = (kc) * 4 + q;                                                \
            int off = ((ch >> 3) * 8 + ((ch & 7) ^ (n & 7))) * 8;                 \
            bf16x8 b = *reinterpret_cast<const bf16x8*>(&sB[n * 256 + off]);      \
            acc[0][nf] = __builtin_amdgcn_mfma_f32_16x16x32_bf16(                 \
                areg[0], b, acc[0][nf], 0, 0, 0);                                 \
            acc[1][nf] = __builtin_amdgcn_mfma_f32_16x16x32_bf16(                 \
                areg[1], b, acc[1][nf], 0, 0, 0);                                 \
        }                                                                         \
        __builtin_amdgcn_s_setprio(0);                                            \
    }

    ALOAD(a0, 0);
    ALOAD(a1, 1);
    ALOAD(a2, 2); COMPK(a0, 0);
    ALOAD(a0, 3); COMPK(a1, 1);
    ALOAD(a1, 4); COMPK(a2, 2);
    ALOAD(a2, 5); COMPK(a0, 3);
    ALOAD(a0, 6); COMPK(a1, 4);
    ALOAD(a1, 7); COMPK(a2, 5);
    COMPK(a0, 6);
    COMPK(a1, 7);
#undef ALOAD
#undef COMPK

    // ---- epilogue: GWAVES passes; pass p = wave p's 32 rows through sC ----
    const float4 asv = *reinterpret_cast<const float4*>(&att_src[lane * 4]);
    const float4 adv = *reinterpret_cast<const float4*>(&att_dst[lane * 4]);
    const int c0 = lane >> 2;            // 16-elem chunk holding lane's 4 feats
    const int p0 = (lane & 3) * 4;       // position within chunk
    for (int p = 0; p < GWAVES; ++p) {
        __syncthreads();
        if (wid == p) {
#pragma unroll
            for (int m = 0; m < 2; ++m)
#pragma unroll
                for (int i = 0; i < 4; ++i) {
                    int rl = m * 16 + (q << 2) + i;        // 0..31
                    const int swz = (rl >> 2) & 3;
#pragma unroll
                    for (int nf = 0; nf < 16; ++nf)
                        sC[rl * 256 + ((nf ^ swz) << 4) + lr] = f2bf(acc[m][nf][i]);
                }
        }
        __syncthreads();
        // coalesced Hb store: 32 rows x 512B (1024 x 16B chunks)
        for (int gc = tid; gc < 1024; gc += GWAVES * 64) {
            int r = gc >> 5;
            int j = gc & 31;
            int cs = (j >> 1) ^ ((r >> 2) & 3);
            const uint4 v = *reinterpret_cast<const uint4*>(
                &sC[r * 256 + (cs << 4) + (j & 1) * 8]);
            int R = brow + p * 32 + r;
            if (R < M)
                *reinterpret_cast<uint4*>(&Hb[(size_t)R * 256 + j * 8]) = v;
        }
        // fused logits: wave-strided rows
        for (int rl = wid; rl < 32; rl += GWAVES) {
            int R = brow + p * 32 + rl;
            const int swz = (rl >> 2) & 3;
            const ushort4 hv = *reinterpret_cast<const ushort4*>(
                &sC[rl * 256 + ((c0 ^ swz) << 4) + p0]);
            float h0 = bf2f(hv.x), h1 = bf2f(hv.y), h2 = bf2f(hv.z), h3 = bf2f(hv.w);
            float ps = h0 * asv.x + h1 * asv.y + h2 * asv.z + h3 * asv.w;
            float pd = h0 * adv.x + h1 * adv.y + h2 * adv.z + h3 * adv.w;
#pragma unroll
            for (int off = 1; off < 16; off <<= 1) {
                ps += __shfl_xor(ps, off, 64);
                pd += __shfl_xor(pd, off, 64);
            }
            if ((lane & 15) == 0 && R < M) {
                int head = lane >> 4;
                asrc[R * HEADS + head] = ps;
                adst[R * HEADS + head] = pd;
            }
        }
    }
}

// ---------------- gather aggregate: one wave per dst, 2 edges in flight -----
__global__ __launch_bounds__(256) void aggregate(const unsigned short* __restrict__ Hb,
                                                 const float* __restrict__ asrc,
                                                 const float* __restrict__ adst,
                                                 const int* __restrict__ cursor,
                                                 const unsigned short* __restrict__ slots,
                                                 const float* __restrict__ bias,
                                                 float* __restrict__ out, int N) {
    int gtid = blockIdx.x * blockDim.x + threadIdx.x;
    int wave = gtid >> 6;
    int lane = threadIdx.x & 63;
    int nwaves = (gridDim.x * blockDim.x) >> 6;
    const int half = lane >> 5;      // 0/1: which edge of the pair
    const int l32 = lane & 31;       // feature slot: [l32*8, l32*8+8)
    const int head = l32 >> 3;
    float bv[8];
#pragma unroll
    for (int i = 0; i < 8; ++i) bv[i] = bias[l32 * 8 + i];

    for (int d = wave; d < N; d += nwaves) {
        const float ad = adst[d * HEADS + head];
        float accv[8];
        float den;
        {   // self-loop handled by half 0 only
            float a = asrc[d * HEADS + head] + ad;
            float w = (half == 0) ? __expf((a > 0.f) ? a : NEG_SLOPE * a) : 0.f;
            const ushort4 h0 = *reinterpret_cast<const ushort4*>(&Hb[(size_t)d * 256 + l32 * 8]);
            const ushort4 h1 = *reinterpret_cast<const ushort4*>(&Hb[(size_t)d * 256 + l32 * 8 + 4]);
            accv[0] = w * bf2f(h0.x); accv[1] = w * bf2f(h0.y);
            accv[2] = w * bf2f(h0.z); accv[3] = w * bf2f(h0.w);
            accv[4] = w * bf2f(h1.x); accv[5] = w * bf2f(h1.y);
            accv[6] = w * bf2f(h1.z); accv[7] = w * bf2f(h1.w);
            den = w;
        }
        const int start = d * SLOT_CAP;
        const int cnt = min(cursor[d], SLOT_CAP);
        int k = half;
        for (; k + 2 < cnt; k += 4) {
            int sA_ = slots[start + k];
            int sB_ = slots[start + k + 2];
            float aA = asrc[sA_ * HEADS + head] + ad;
            float aB = asrc[sB_ * HEADS + head] + ad;
            const ushort4 a0 = *reinterpret_cast<const ushort4*>(&Hb[(size_t)sA_ * 256 + l32 * 8]);
            const ushort4 a1 = *reinterpret_cast<const ushort4*>(&Hb[(size_t)sA_ * 256 + l32 * 8 + 4]);
            const ushort4 b0 = *reinterpret_cast<const ushort4*>(&Hb[(size_t)sB_ * 256 + l32 * 8]);
            const ushort4 b1 = *reinterpret_cast<const ushort4*>(&Hb[(size_t)sB_ * 256 + l32 * 8 + 4]);
            float wA = __expf((aA > 0.f) ? aA : NEG_SLOPE * aA);
            float wB = __expf((aB > 0.f) ? aB : NEG_SLOPE * aB);
            accv[0] += wA * bf2f(a0.x) + wB * bf2f(b0.x);
            accv[1] += wA * bf2f(a0.y) + wB * bf2f(b0.y);
            accv[2] += wA * bf2f(a0.z) + wB * bf2f(b0.z);
            accv[3] += wA * bf2f(a0.w) + wB * bf2f(b0.w);
            accv[4] += wA * bf2f(a1.x) + wB * bf2f(b1.x);
            accv[5] += wA * bf2f(a1.y) + wB * bf2f(b1.y);
            accv[6] += wA * bf2f(a1.z) + wB * bf2f(b1.z);
            accv[7] += wA * bf2f(a1.w) + wB * bf2f(b1.w);
            den += wA + wB;
        }
        for (; k < cnt; k += 2) {
            int s0 = slots[start + k];
            float a0f = asrc[s0 * HEADS + head] + ad;
            const ushort4 u0 = *reinterpret_cast<const ushort4*>(&Hb[(size_t)s0 * 256 + l32 * 8]);
            const ushort4 u1 = *reinterpret_cast<const ushort4*>(&Hb[(size_t)s0 * 256 + l32 * 8 + 4]);
            float w0 = __expf((a0f > 0.f) ? a0f : NEG_SLOPE * a0f);
            accv[0] += w0 * bf2f(u0.x); accv[1] += w0 * bf2f(u0.y);
            accv[2] += w0 * bf2f(u0.z); accv[3] += w0 * bf2f(u0.w);
            accv[4] += w0 * bf2f(u1.x); accv[5] += w0 * bf2f(u1.y);
            accv[6] += w0 * bf2f(u1.z); accv[7] += w0 * bf2f(u1.w);
            den += w0;
        }
#pragma unroll
        for (int i = 0; i < 8; ++i) accv[i] += __shfl_xor(accv[i], 32, 64);
        den += __shfl_xor(den, 32, 64);
        if (half == 0) {
            const float inv = 1.f / den;
            float4 r0, r1;
            r0.x = fmaxf(accv[0] * inv + bv[0], 0.f);
            r0.y = fmaxf(accv[1] * inv + bv[1], 0.f);
            r0.z = fmaxf(accv[2] * inv + bv[2], 0.f);
            r0.w = fmaxf(accv[3] * inv + bv[3], 0.f);
            r1.x = fmaxf(accv[4] * inv + bv[4], 0.f);
            r1.y = fmaxf(accv[5] * inv + bv[5], 0.f);
            r1.z = fmaxf(accv[6] * inv + bv[6], 0.f);
            r1.w = fmaxf(accv[7] * inv + bv[7], 0.f);
            *reinterpret_cast<float4*>(&out[(size_t)d * 256 + l32 * 8]) = r0;
            *reinterpret_cast<float4*>(&out[(size_t)d * 256 + l32 * 8 + 4]) = r1;
        }
    }
}

extern "C" void kernel_launch(void* const* d_in, const int* in_sizes, int n_in,
                              void* d_out, int out_size, void* d_ws, size_t ws_size,
                              hipStream_t stream) {
    const float* x       = (const float*)d_in[0];
    const int*   ei      = (const int*)d_in[1];      // harness converts int64 -> int32
    const float* W       = (const float*)d_in[2];
    const float* att_src = (const float*)d_in[3];
    const float* att_dst = (const float*)d_in[4];
    const float* bias    = (const float*)d_in[5];
    float*       out     = (float*)d_out;

    const int N = in_sizes[0] / IN_FEAT;   // 50000 (< 65536: slots are uint16)
    const int E = in_sizes[1] / 2;         // 800000
    const int ROWS = GWAVES * 32;          // 192 rows per gemm block
    const int nGB = (N + ROWS - 1) / ROWS; // 261 blocks ~ one full CU round
    const int Npad = nGB * ROWS;

    // workspace layout
    unsigned short* Hb = (unsigned short*)d_ws;               // Npad*256 bf16
    float* asrc       = (float*)(Hb + (size_t)Npad * IN_FEAT);
    float* adst       = asrc + (size_t)N * HEADS;
    int*   cursor     = (int*)(adst + (size_t)N * HEADS);     // N (degree after scatter)
    unsigned short* slots = (unsigned short*)(cursor + N);    // N*64 uint16 slot CSR
    unsigned short* Wtb = slots + (size_t)N * SLOT_CAP;       // 256*256 bf16

    hipMemsetAsync(cursor, 0, (size_t)N * sizeof(int), stream);

    // XCD-partitioned slot scatter || W bf16 pre-convert — one kernel
    {
        const int NS = 2048;                       // multiple of 8, scatter first
        cvt_scatter<<<NS + 32, 256, 0, stream>>>(ei, W, Wtb, cursor, slots, E, N, NS);
    }

    // weight-stationary GEMM (A from f32 X, distance-2 prefetch) + logits
    gemm_ws<<<nGB, GWAVES * 64, 0, stream>>>(x, Wtb, att_src, att_dst,
                                             Hb, asrc, adst, N);

    aggregate<<<(N * 64 + 255) / 256, 256, 0, stream>>>(Hb, asrc, adst, cursor, slots,
                                                        bias, out, N);
}

// Round 24
// 142.547 us; speedup vs baseline: 1.2362x; 1.2362x over previous
//
#include <hip/hip_runtime.h>
#include <hip/hip_bf16.h>

#define IN_FEAT 256
#define HEADS 4
#define OUT_FEAT 64
#define NEG_SLOPE 0.2f
#define SLOT_CAP 64
#define NGB 256               // gemm grid: exactly one block per CU

typedef __bf16 bf16x8 __attribute__((ext_vector_type(8)));
typedef float f32x4 __attribute__((ext_vector_type(4)));

__device__ inline unsigned short f2bf(float f) {
    union { float f; unsigned u; } v; v.f = f;
    unsigned r = v.u + 0x7FFF + ((v.u >> 16) & 1);   // RNE, finite inputs
    return (unsigned short)(r >> 16);
}
__device__ inline float bf2f(unsigned short u) {
    union { unsigned u; float f; } v; v.u = ((unsigned)u) << 16; return v.f;
}

// ---------------- merged: XCD-partitioned slot scatter + W bf16 convert -----
__global__ __launch_bounds__(256) void cvt_scatter(const int* __restrict__ ei,
                                                   const float* __restrict__ W,
                                                   unsigned short* __restrict__ Wtb,
                                                   int* __restrict__ cursor,
                                                   unsigned short* __restrict__ slots,
                                                   int E, int N, int NS) {
    const int tid = threadIdx.x;
    if ((int)blockIdx.x < NS) {
        // ---- XCD-partitioned scatter (keeps each dst-range in one L2) ----
        const int part = blockIdx.x & 7;
        const int rsize = (N + 7) >> 3;
        const int lo = part * rsize;
        const int hi = min(lo + rsize, N);
        int lid = ((int)blockIdx.x >> 3) * 256 + tid;
        int lstride = (NS >> 3) * 256;
        for (int e = lid; e < E; e += lstride) {
            int d = ei[E + e];
            if (d < lo || d >= hi) continue;
            int s = ei[e];
            if ((unsigned)s >= (unsigned)N) continue;
            int pos = atomicAdd(&cursor[d], 1);
            if (pos < SLOT_CAP) slots[d * SLOT_CAP + pos] = (unsigned short)s;
        }
        return;
    }
    // ---- W -> Wtb (transposed bf16, pre-swizzled): 8192 chunk-pairs ----
    int idx = ((int)blockIdx.x - NS) * 256 + tid;
    if (idx >= 256 * 32) return;
    int n = idx >> 5, j = idx & 31;
    int g = j >> 3, c = j & 7;
    ushort4 p0, p1;
    p0.x = f2bf(W[(size_t)(j * 8 + 0) * 256 + n]);
    p0.y = f2bf(W[(size_t)(j * 8 + 1) * 256 + n]);
    p0.z = f2bf(W[(size_t)(j * 8 + 2) * 256 + n]);
    p0.w = f2bf(W[(size_t)(j * 8 + 3) * 256 + n]);
    p1.x = f2bf(W[(size_t)(j * 8 + 4) * 256 + n]);
    p1.y = f2bf(W[(size_t)(j * 8 + 5) * 256 + n]);
    p1.z = f2bf(W[(size_t)(j * 8 + 6) * 256 + n]);
    p1.w = f2bf(W[(size_t)(j * 8 + 7) * 256 + n]);
    unsigned short* dst = &Wtb[(size_t)n * 256 + (g * 8 + (c ^ (n & 7))) * 8];
    *reinterpret_cast<ushort4*>(dst) = p0;
    *reinterpret_cast<ushort4*>(dst + 4) = p1;
}

// ---------------- weight-stationary GEMM: Hb = bf16(X @ Wtb^T) + logits -----
// Wtb (128 KB, pre-swizzled) stationary in LDS. 8 waves; wave w owns the
// 32-row tile (blockIdx + w*NGB) — grid is EXACTLY 256 blocks (1/CU, one
// round, no idle CUs). A straight from f32 X (global->reg, f2bf, distance-1
// double buffer), B via ds_read_b128, no main-loop barriers.
__global__ __launch_bounds__(512) void gemm_ws(
        const float* __restrict__ X, const unsigned short* __restrict__ Wtb,
        const float* __restrict__ att_src, const float* __restrict__ att_dst,
        unsigned short* __restrict__ Hb, float* __restrict__ asrc,
        float* __restrict__ adst, int M) {
    __shared__ __align__(16) unsigned short sB[256 * 256];  // 128 KB, stationary
    __shared__ __align__(16) unsigned short sC[32 * 256];   // 16 KB epilogue
    const int tid = threadIdx.x;
    const int lane = tid & 63;
    const int wid = tid >> 6;
    const int q = lane >> 4;          // 0..3: k-subchunk
    const int lr = lane & 15;         // row-in-fragment / col-in-fragment
    const int T = (M + 31) >> 5;      // number of 32-row tiles (1563)

    // ---- prologue: copy pre-swizzled Wtb into LDS (8192 uint4) ----
    {
        const uint4* W4 = reinterpret_cast<const uint4*>(Wtb);
        uint4* dB = reinterpret_cast<uint4*>(sB);
#pragma unroll
        for (int t = 0; t < 16; ++t) dB[t * 512 + tid] = W4[t * 512 + tid];
    }
    __syncthreads();

    const int tile = (int)blockIdx.x + wid * NGB;   // this wave's tile index
    const int r0 = tile * 32;

    f32x4 acc[2][16] = {};
    bf16x8 af[2], naf[2];

    // A fragment: row r, logical chunk ch (8 bf16) read from f32 X directly.
    // Rows clamp to M-1 (valid memory; results discarded by R<M guards).
#define ALOAD(dst, kc)                                                            \
    {                                                                             \
        int ch = (kc) * 4 + q;                                                    \
        _Pragma("unroll")                                                         \
        for (int m = 0; m < 2; ++m) {                                             \
            int r = r0 + m * 16 + lr;                                             \
            if (r >= M) r = M - 1;                                                \
            const float4 x0 = *reinterpret_cast<const float4*>(                   \
                &X[(size_t)r * 256 + ch * 8]);                                    \
            const float4 x1 = *reinterpret_cast<const float4*>(                   \
                &X[(size_t)r * 256 + ch * 8 + 4]);                                \
            union { ushort4 u2[2]; bf16x8 v; } cv;                                \
            cv.u2[0].x = f2bf(x0.x); cv.u2[0].y = f2bf(x0.y);                     \
            cv.u2[0].z = f2bf(x0.z); cv.u2[0].w = f2bf(x0.w);                     \
            cv.u2[1].x = f2bf(x1.x); cv.u2[1].y = f2bf(x1.y);                     \
            cv.u2[1].z = f2bf(x1.z); cv.u2[1].w = f2bf(x1.w);                     \
            dst[m] = cv.v;                                                        \
        }                                                                         \
    }

    if (tile < T) {
        ALOAD(af, 0);
#pragma unroll
        for (int kc = 0; kc < 8; ++kc) {
            if (kc < 7) ALOAD(naf, kc + 1);
#pragma unroll
            for (int nf = 0; nf < 16; ++nf) {
                int n = nf * 16 + lr;
                int ch = kc * 4 + q;
                int off = ((ch >> 3) * 8 + ((ch & 7) ^ (n & 7))) * 8;
                bf16x8 b = *reinterpret_cast<const bf16x8*>(&sB[n * 256 + off]);
                acc[0][nf] = __builtin_amdgcn_mfma_f32_16x16x32_bf16(af[0], b, acc[0][nf], 0, 0, 0);
                acc[1][nf] = __builtin_amdgcn_mfma_f32_16x16x32_bf16(af[1], b, acc[1][nf], 0, 0, 0);
            }
            af[0] = naf[0];
            af[1] = naf[1];
        }
    }
#undef ALOAD

    // ---- epilogue: 8 passes; pass p = wave p's 32-row tile through sC ----
    const float4 asv = *reinterpret_cast<const float4*>(&att_src[lane * 4]);
    const float4 adv = *reinterpret_cast<const float4*>(&att_dst[lane * 4]);
    const int c0 = lane >> 2;            // 16-elem chunk holding lane's 4 feats
    const int p0 = (lane & 3) * 4;       // position within chunk
    for (int p = 0; p < 8; ++p) {
        const int tp = (int)blockIdx.x + p * NGB;
        if (tp >= T) break;              // uniform across block (tiles strided)
        const int rbase = tp * 32;
        __syncthreads();
        if (wid == p) {
#pragma unroll
            for (int m = 0; m < 2; ++m)
#pragma unroll
                for (int i = 0; i < 4; ++i) {
                    int rl = m * 16 + (q << 2) + i;        // 0..31
                    const int swz = (rl >> 2) & 3;
#pragma unroll
                    for (int nf = 0; nf < 16; ++nf)
                        sC[rl * 256 + ((nf ^ swz) << 4) + lr] = f2bf(acc[m][nf][i]);
                }
        }
        __syncthreads();
        // coalesced Hb store: 32 rows x 512B (1024 x 16B chunks)
#pragma unroll
        for (int it = 0; it < 2; ++it) {
            int gc = it * 512 + tid;        // 16B chunk id, 32 per row
            int r = gc >> 5;
            int j = gc & 31;
            int cs = (j >> 1) ^ ((r >> 2) & 3);
            const uint4 v = *reinterpret_cast<const uint4*>(
                &sC[r * 256 + (cs << 4) + (j & 1) * 8]);
            int R = rbase + r;
            if (R < M)
                *reinterpret_cast<uint4*>(&Hb[(size_t)R * 256 + j * 8]) = v;
        }
        // fused logits: 4 rows per wave
#pragma unroll
        for (int rr = 0; rr < 4; ++rr) {
            int rl = wid * 4 + rr;
            int R = rbase + rl;
            const int swz = (rl >> 2) & 3;
            const ushort4 hv = *reinterpret_cast<const ushort4*>(
                &sC[rl * 256 + ((c0 ^ swz) << 4) + p0]);
            float h0 = bf2f(hv.x), h1 = bf2f(hv.y), h2 = bf2f(hv.z), h3 = bf2f(hv.w);
            float ps = h0 * asv.x + h1 * asv.y + h2 * asv.z + h3 * asv.w;
            float pd = h0 * adv.x + h1 * adv.y + h2 * adv.z + h3 * adv.w;
#pragma unroll
            for (int off = 1; off < 16; off <<= 1) {
                ps += __shfl_xor(ps, off, 64);
                pd += __shfl_xor(pd, off, 64);
            }
            if ((lane & 15) == 0 && R < M) {
                int head = lane >> 4;
                asrc[R * HEADS + head] = ps;
                adst[R * HEADS + head] = pd;
            }
        }
    }
}

// ---------------- gather aggregate: one wave per dst, 2 edges in flight -----
// CSR is implicit: segment d lives at slots[d*64 .. d*64+cursor[d])
__global__ __launch_bounds__(256) void aggregate(const unsigned short* __restrict__ Hb,
                                                 const float* __restrict__ asrc,
                                                 const float* __restrict__ adst,
                                                 const int* __restrict__ cursor,
                                                 const unsigned short* __restrict__ slots,
                                                 const float* __restrict__ bias,
                                                 float* __restrict__ out, int N) {
    int gtid = blockIdx.x * blockDim.x + threadIdx.x;
    int wave = gtid >> 6;
    int lane = threadIdx.x & 63;
    int nwaves = (gridDim.x * blockDim.x) >> 6;
    const int half = lane >> 5;      // 0/1: which edge of the pair
    const int l32 = lane & 31;       // feature slot: [l32*8, l32*8+8)
    const int head = l32 >> 3;
    float bv[8];
#pragma unroll
    for (int i = 0; i < 8; ++i) bv[i] = bias[l32 * 8 + i];

    for (int d = wave; d < N; d += nwaves) {
        const float ad = adst[d * HEADS + head];
        float accv[8];
        float den;
        {   // self-loop handled by half 0 only
            float a = asrc[d * HEADS + head] + ad;
            float w = (half == 0) ? __expf((a > 0.f) ? a : NEG_SLOPE * a) : 0.f;
            const ushort4 h0 = *reinterpret_cast<const ushort4*>(&Hb[(size_t)d * 256 + l32 * 8]);
            const ushort4 h1 = *reinterpret_cast<const ushort4*>(&Hb[(size_t)d * 256 + l32 * 8 + 4]);
            accv[0] = w * bf2f(h0.x); accv[1] = w * bf2f(h0.y);
            accv[2] = w * bf2f(h0.z); accv[3] = w * bf2f(h0.w);
            accv[4] = w * bf2f(h1.x); accv[5] = w * bf2f(h1.y);
            accv[6] = w * bf2f(h1.z); accv[7] = w * bf2f(h1.w);
            den = w;
        }
        const int start = d * SLOT_CAP;
        const int cnt = min(cursor[d], SLOT_CAP);
        int k = half;
        for (; k + 2 < cnt; k += 4) {
            int sA_ = slots[start + k];
            int sB_ = slots[start + k + 2];
            float aA = asrc[sA_ * HEADS + head] + ad;
            float aB = asrc[sB_ * HEADS + head] + ad;
            const ushort4 a0 = *reinterpret_cast<const ushort4*>(&Hb[(size_t)sA_ * 256 + l32 * 8]);
            const ushort4 a1 = *reinterpret_cast<const ushort4*>(&Hb[(size_t)sA_ * 256 + l32 * 8 + 4]);
            const ushort4 b0 = *reinterpret_cast<const ushort4*>(&Hb[(size_t)sB_ * 256 + l32 * 8]);
            const ushort4 b1 = *reinterpret_cast<const ushort4*>(&Hb[(size_t)sB_ * 256 + l32 * 8 + 4]);
            float wA = __expf((aA > 0.f) ? aA : NEG_SLOPE * aA);
            float wB = __expf((aB > 0.f) ? aB : NEG_SLOPE * aB);
            accv[0] += wA * bf2f(a0.x) + wB * bf2f(b0.x);
            accv[1] += wA * bf2f(a0.y) + wB * bf2f(b0.y);
            accv[2] += wA * bf2f(a0.z) + wB * bf2f(b0.z);
            accv[3] += wA * bf2f(a0.w) + wB * bf2f(b0.w);
            accv[4] += wA * bf2f(a1.x) + wB * bf2f(b1.x);
            accv[5] += wA * bf2f(a1.y) + wB * bf2f(b1.y);
            accv[6] += wA * bf2f(a1.z) + wB * bf2f(b1.z);
            accv[7] += wA * bf2f(a1.w) + wB * bf2f(b1.w);
            den += wA + wB;
        }
        for (; k < cnt; k += 2) {
            int s0 = slots[start + k];
            float a0f = asrc[s0 * HEADS + head] + ad;
            const ushort4 u0 = *reinterpret_cast<const ushort4*>(&Hb[(size_t)s0 * 256 + l32 * 8]);
            const ushort4 u1 = *reinterpret_cast<const ushort4*>(&Hb[(size_t)s0 * 256 + l32 * 8 + 4]);
            float w0 = __expf((a0f > 0.f) ? a0f : NEG_SLOPE * a0f);
            accv[0] += w0 * bf2f(u0.x); accv[1] += w0 * bf2f(u0.y);
            accv[2] += w0 * bf2f(u0.z); accv[3] += w0 * bf2f(u0.w);
            accv[4] += w0 * bf2f(u1.x); accv[5] += w0 * bf2f(u1.y);
            accv[6] += w0 * bf2f(u1.z); accv[7] += w0 * bf2f(u1.w);
            den += w0;
        }
#pragma unroll
        for (int i = 0; i < 8; ++i) accv[i] += __shfl_xor(accv[i], 32, 64);
        den += __shfl_xor(den, 32, 64);
        if (half == 0) {
            const float inv = 1.f / den;
            float4 r0, r1;
            r0.x = fmaxf(accv[0] * inv + bv[0], 0.f);
            r0.y = fmaxf(accv[1] * inv + bv[1], 0.f);
            r0.z = fmaxf(accv[2] * inv + bv[2], 0.f);
            r0.w = fmaxf(accv[3] * inv + bv[3], 0.f);
            r1.x = fmaxf(accv[4] * inv + bv[4], 0.f);
            r1.y = fmaxf(accv[5] * inv + bv[5], 0.f);
            r1.z = fmaxf(accv[6] * inv + bv[6], 0.f);
            r1.w = fmaxf(accv[7] * inv + bv[7], 0.f);
            *reinterpret_cast<float4*>(&out[(size_t)d * 256 + l32 * 8]) = r0;
            *reinterpret_cast<float4*>(&out[(size_t)d * 256 + l32 * 8 + 4]) = r1;
        }
    }
}

extern "C" void kernel_launch(void* const* d_in, const int* in_sizes, int n_in,
                              void* d_out, int out_size, void* d_ws, size_t ws_size,
                              hipStream_t stream) {
    const float* x       = (const float*)d_in[0];
    const int*   ei      = (const int*)d_in[1];      // harness converts int64 -> int32
    const float* W       = (const float*)d_in[2];
    const float* att_src = (const float*)d_in[3];
    const float* att_dst = (const float*)d_in[4];
    const float* bias    = (const float*)d_in[5];
    float*       out     = (float*)d_out;

    const int N = in_sizes[0] / IN_FEAT;   // 50000 (< 65536: slots are uint16)
    const int E = in_sizes[1] / 2;         // 800000
    const int Npad = (((N + 31) / 32) + 0) * 32 + 32 * NGB;  // safety pad (tiles strided)

    // workspace layout
    unsigned short* Hb = (unsigned short*)d_ws;               // >= Npad*256 bf16
    float* asrc       = (float*)(Hb + (size_t)Npad * IN_FEAT);
    float* adst       = asrc + (size_t)N * HEADS;
    int*   cursor     = (int*)(adst + (size_t)N * HEADS);     // N (degree after scatter)
    unsigned short* slots = (unsigned short*)(cursor + N);    // N*64 uint16 slot CSR
    unsigned short* Wtb = slots + (size_t)N * SLOT_CAP;       // 256*256 bf16

    hipMemsetAsync(cursor, 0, (size_t)N * sizeof(int), stream);

    // XCD-partitioned slot scatter || W bf16 pre-convert — one kernel
    {
        const int NS = 2048;                       // multiple of 8, scatter first
        cvt_scatter<<<NS + 32, 256, 0, stream>>>(ei, W, Wtb, cursor, slots, E, N, NS);
    }

    // weight-stationary GEMM: 256 blocks (1/CU), wave-strided 32-row tiles
    gemm_ws<<<NGB, 512, 0, stream>>>(x, Wtb, att_src, att_dst,
                                     Hb, asrc, adst, N);

    aggregate<<<(N * 64 + 255) / 256, 256, 0, stream>>>(Hb, asrc, adst, cursor, slots,
                                                        bias, out, N);
}